// Round 6
// baseline (392.091 us; speedup 1.0000x reference)
//
#include <hip/hip_runtime.h>
#include <math.h>

// Problem constants
#define D_ELEMS 25088   // C*H*W = 512*7*7
#define D4      6272    // D_ELEMS / 4
#define N_MEM   2000
#define B_KEYS  32
#define PI_2F   1.570795f   // 3.14159 / 2, matches reference
#define EPSF    1e-8f
#define NSLICE  49          // k-slices for k_dots_mfma
#define KSLICE  512         // 25088 / 49
#define KSTEPS  16          // KSLICE / 32
#define NWAVES  (125 * NSLICE)   // 6125 (nt,s) wave-tasks
#define RTILE   100         // n-rows per LDS w-tile in k_read

using short8 = __attribute__((ext_vector_type(8))) short;   // 8 bf16 A/B frag
using short4v = __attribute__((ext_vector_type(4))) short;
using f32x4  = __attribute__((ext_vector_type(4))) float;   // C/D frag

// ws layout (floats):
//   keyb (bf16 keys, as shorts)   : [0, 401408)
//   dots_part [49][2000][32]      : [401408, 3537408)
//   mn2_part  [49][2000]          : [3537408, 3635408)
//   dots      [2000][32]          : [3635408, 3699408)
//   mn2       [2000]              : [3699408, 3701408)
//   w         [2000][32]          : [3701440, 3765440)   (16B aligned)
//   partial [ns][32][25088]       : [3765440, +ns*802816) (16B aligned)

__device__ inline short f2bf(float x) {   // fp32 -> bf16 RNE (inputs finite)
    union { float f; unsigned u; } v; v.f = x;
    unsigned r = v.u + 0x7fffu + ((v.u >> 16) & 1u);
    return (short)(r >> 16);
}

// Convert keys fp32 -> bf16. 802816 elems, 4 per thread, grid 784*256.
__global__ __launch_bounds__(256) void k_prep(const float* __restrict__ key,
                                              short* __restrict__ keyb) {
    const int i = blockIdx.x * 256 + threadIdx.x;   // float4 index
    const float4 f = ((const float4*)key)[i];
    short4v s; s[0] = f2bf(f.x); s[1] = f2bf(f.y); s[2] = f2bf(f.z); s[3] = f2bf(f.w);
    ((short4v*)keyb)[i] = s;
}

// dots_part[s][n][b] = sum_{k in slice s} key[b][k]*mem[n][k]  (bf16 MFMA)
// mn2_part[s][n]     = sum_{k in slice s} mem[n][k]^2          (fp32)
// 6125 wave-tasks PACKED 4 waves per 256-thread block (1532 blocks):
// single-wave workgroups hit the per-CU workgroup cap (~16), leaving half
// the wave slots empty -- with depth-1 prefetch (duty ~10%/wave) that was
// the R5 throttle. 4-wave blocks restore 32 resident waves/CU.
__global__ __launch_bounds__(256) void k_dots_mfma(const short* __restrict__ keyb,
                                                  const float* __restrict__ mem,
                                                  float* __restrict__ dots_part,
                                                  float* __restrict__ mn2_part) {
    const int wid = blockIdx.x * 4 + (threadIdx.x >> 6);  // wave task id
    if (wid >= NWAVES) return;                             // 3-slot pad
    const int nt   = wid / NSLICE;            // 0..124
    const int s    = wid % NSLICE;            // 0..48
    const int n0   = nt * 16;
    const int lane = threadIdx.x & 63;
    const int quad = lane >> 4;
    const int l16  = lane & 15;
    const int k0   = s * KSLICE + quad * 8;   // this lane's k base (floats)

    const short* a0p = keyb + (size_t)l16 * D_ELEMS + k0;          // keys 0..15
    const short* a1p = keyb + (size_t)(16 + l16) * D_ELEMS + k0;   // keys 16..31
    const float4* bp = (const float4*)(mem + (size_t)(n0 + l16) * D_ELEMS + k0);

    f32x4 acc0 = {0.f, 0.f, 0.f, 0.f};
    f32x4 acc1 = {0.f, 0.f, 0.f, 0.f};
    float msq = 0.f;

    // depth-1 prefetch: loads for step t+1 issue before the cvt+mfma of t
    short8 a0 = *(const short8*)a0p;
    short8 a1 = *(const short8*)a1p;
    float4 f0 = bp[0], f1 = bp[1];

    for (int t = 0; t < KSTEPS; ++t) {
        const short8 a0c = a0, a1c = a1;
        const float4 f0c = f0, f1c = f1;
        if (t + 1 < KSTEPS) {                 // wave-uniform branch
            a0 = *(const short8*)(a0p + (t + 1) * 32);
            a1 = *(const short8*)(a1p + (t + 1) * 32);
            f0 = bp[(t + 1) * 8];
            f1 = bp[(t + 1) * 8 + 1];
        }
        msq += f0c.x * f0c.x + f0c.y * f0c.y + f0c.z * f0c.z + f0c.w * f0c.w
             + f1c.x * f1c.x + f1c.y * f1c.y + f1c.z * f1c.z + f1c.w * f1c.w;
        short8 b;
        b[0] = f2bf(f0c.x); b[1] = f2bf(f0c.y); b[2] = f2bf(f0c.z); b[3] = f2bf(f0c.w);
        b[4] = f2bf(f1c.x); b[5] = f2bf(f1c.y); b[6] = f2bf(f1c.z); b[7] = f2bf(f1c.w);
        acc0 = __builtin_amdgcn_mfma_f32_16x16x32_bf16(a0c, b, acc0, 0, 0, 0);
        acc1 = __builtin_amdgcn_mfma_f32_16x16x32_bf16(a1c, b, acc1, 0, 0, 0);
    }

    // D[row=quad*4+r][col=l16]; row = key index (per m-half), col = n index
    float* dp = dots_part + (size_t)(s * N_MEM + n0 + l16) * B_KEYS;
#pragma unroll
    for (int r = 0; r < 4; ++r) {
        dp[quad * 4 + r]      = acc0[r];
        dp[16 + quad * 4 + r] = acc1[r];
    }

    // reduce msq across the 4 quads of each n-row (lanes l16, l16+16, ...)
    msq += __shfl_xor(msq, 16, 64);
    msq += __shfl_xor(msq, 32, 64);
    if (lane < 16) mn2_part[s * N_MEM + n0 + lane] = msq;
}

// Collapse the 49 slice partials: dots[n][b], mn2[n]. Coalesced. grid 250.
__global__ __launch_bounds__(256) void k_reduce(const float* __restrict__ dots_part,
                                                const float* __restrict__ mn2_part,
                                                float* __restrict__ dots,
                                                float* __restrict__ mn2) {
    const int gid = blockIdx.x * 256 + threadIdx.x;   // 0..63999
    float ds = 0.f;
#pragma unroll
    for (int s = 0; s < NSLICE; ++s) ds += dots_part[s * (N_MEM * B_KEYS) + gid];
    dots[gid] = ds;
    if (gid < N_MEM) {
        float ms = 0.f;
#pragma unroll
        for (int s = 0; s < NSLICE; ++s) ms += mn2_part[s * N_MEM + gid];
        mn2[gid] = ms;
    }
}

// per-b: knorm (own key, 100KB/block) -> cos -> tan -> softmax over n -> w.
__global__ __launch_bounds__(512) void k_softmax(const float* __restrict__ key,
                                                 const float* __restrict__ dots,
                                                 const float* __restrict__ mn2,
                                                 float* __restrict__ w) {
    const int b   = blockIdx.x;
    const int tid = threadIdx.x;
    __shared__ float sred[512];
    __shared__ float xbuf[N_MEM];

    const float4* K4 = (const float4*)(key + (size_t)b * D_ELEMS);
    float ks = 0.f;
    for (int i = tid; i < D4; i += 512) {
        const float4 kf = K4[i];
        ks += kf.x * kf.x + kf.y * kf.y + kf.z * kf.z + kf.w * kf.w;
    }
    sred[tid] = ks;
    __syncthreads();
    for (int o = 256; o; o >>= 1) {
        if (tid < o) sred[tid] += sred[tid + o];
        __syncthreads();
    }
    const float knorm = fmaxf(sqrtf(sred[0]), EPSF);
    __syncthreads();

    float mx = -1e30f;
    for (int n = tid; n < N_MEM; n += 512) {
        const float mn = fmaxf(sqrtf(mn2[n]), EPSF);
        const float x  = __tanf((dots[n * B_KEYS + b] / (knorm * mn)) * PI_2F);
        xbuf[n] = x;
        mx = fmaxf(mx, x);
    }
    sred[tid] = mx;
    __syncthreads();
    for (int o = 256; o; o >>= 1) {
        if (tid < o) sred[tid] = fmaxf(sred[tid], sred[tid + o]);
        __syncthreads();
    }
    mx = sred[0];
    __syncthreads();

    float sm = 0.f;
    for (int n = tid; n < N_MEM; n += 512) {   // cache exp in xbuf (own slots)
        const float e = __expf(xbuf[n] - mx);
        xbuf[n] = e;
        sm += e;
    }
    sred[tid] = sm;
    __syncthreads();
    for (int o = 256; o; o >>= 1) {
        if (tid < o) sred[tid] += sred[tid + o];
        __syncthreads();
    }
    const float inv = 1.f / sred[0];

    for (int n = tid; n < N_MEM; n += 512)
        w[n * B_KEYS + b] = xbuf[n] * inv;
}

// partial[s][b][d] = sum_{n in split s} w[n][b] * mem[n][d]
// REWRITE: one thread owns ONE float4 column for ALL 32 b (acc[32][4] =
// 128 VGPRs, fully unrolled -> registers). 128-thread blocks, 49 d-blocks
// cover 6272 float4 exactly; grid 49 x ns. Each mem element is loaded
// exactly ONCE per split (the old layout had all 4 waves of a block
// loading identical addresses = 4x redundant VMEM issue). w broadcast from
// a 100-row LDS tile (uniform-address reads are conflict-free broadcasts).
__global__ __launch_bounds__(128, 2) void k_read(const float* __restrict__ mem,
                                                 const float* __restrict__ w,
                                                 float* __restrict__ partial,
                                                 int nPerS) {
    const int db  = blockIdx.x % 49;
    const int s   = blockIdx.x / 49;
    const int n0  = s * nPerS;
    const int tid = threadIdx.x;                // 0..127
    const int d4  = db * 128 + tid;             // float4 column, < 6272

    const float4* M4 = (const float4*)mem;
    const float4* W4 = (const float4*)w;        // [n][8] float4
    __shared__ float4 wls[RTILE * 8];           // 100 n x 32 b = 12.8 KB

    float acc[32][4];
#pragma unroll
    for (int i = 0; i < 32; ++i) {
        acc[i][0] = 0.f; acc[i][1] = 0.f; acc[i][2] = 0.f; acc[i][3] = 0.f;
    }

    for (int c0 = 0; c0 < nPerS; c0 += RTILE) { // nPerS is a multiple of 100
        __syncthreads();
        for (int i = tid; i < RTILE * 8; i += 128)
            wls[i] = W4[(size_t)(n0 + c0) * 8 + i];
        __syncthreads();

        const float4* mp = M4 + (size_t)(n0 + c0) * D4 + d4;
#pragma unroll 4
        for (int nn = 0; nn < RTILE; ++nn) {
            const float4 mc = mp[(size_t)nn * D4];
#pragma unroll
            for (int q = 0; q < 8; ++q) {
                const float4 wq = wls[nn * 8 + q];
                const int b0 = q * 4;
                acc[b0+0][0] += wq.x * mc.x; acc[b0+0][1] += wq.x * mc.y;
                acc[b0+0][2] += wq.x * mc.z; acc[b0+0][3] += wq.x * mc.w;
                acc[b0+1][0] += wq.y * mc.x; acc[b0+1][1] += wq.y * mc.y;
                acc[b0+1][2] += wq.y * mc.z; acc[b0+1][3] += wq.y * mc.w;
                acc[b0+2][0] += wq.z * mc.x; acc[b0+2][1] += wq.z * mc.y;
                acc[b0+2][2] += wq.z * mc.z; acc[b0+2][3] += wq.z * mc.w;
                acc[b0+3][0] += wq.w * mc.x; acc[b0+3][1] += wq.w * mc.y;
                acc[b0+3][2] += wq.w * mc.z; acc[b0+3][3] += wq.w * mc.w;
            }
        }
    }

    float4* P4 = (float4*)partial;
#pragma unroll
    for (int b = 0; b < 32; ++b)
        P4[(size_t)(s * B_KEYS + b) * D4 + d4] =
            make_float4(acc[b][0], acc[b][1], acc[b][2], acc[b][3]);
}

__global__ __launch_bounds__(256) void k_finish(const float* __restrict__ partial,
                                                float* __restrict__ out, int ns) {
    const int i = blockIdx.x * 256 + threadIdx.x;   // float4 index, grid 784*256
    const float4* P4 = (const float4*)partial;
    float4 sum = P4[i];
    for (int s = 1; s < ns; ++s) {
        const float4 p = P4[(size_t)s * (B_KEYS * D4) + i];
        sum.x += p.x; sum.y += p.y; sum.z += p.z; sum.w += p.w;
    }
    ((float4*)out)[i] = sum;
}

extern "C" void kernel_launch(void* const* d_in, const int* in_sizes, int n_in,
                              void* d_out, int out_size, void* d_ws, size_t ws_size,
                              hipStream_t stream) {
    (void)in_sizes; (void)n_in; (void)out_size;
    const float* key = (const float*)d_in[0];
    const float* mem = (const float*)d_in[1];
    float* out = (float*)d_out;
    float* ws  = (float*)d_ws;

    short* keyb      = (short*)ws;      // 802816 shorts = 401408 floats
    float* dots_part = ws + 401408;     // 3136000 floats
    float* mn2_part  = ws + 3537408;    // 98000 floats
    float* dots      = ws + 3635408;    // 64000 floats
    float* mn2       = ws + 3699408;    // 2000 floats
    float* w         = ws + 3701440;    // 64000 floats (16B aligned)
    float* part      = ws + 3765440;    // ns * 802816 floats (16B aligned)

    // ns ladder keeps nPerS a multiple of RTILE=100: 20, 10, 5, 2, 1
    int ns = 20;
    while (ns > 1 && (size_t)(3765440 + (size_t)ns * 802816) * 4 > ws_size)
        ns = (ns == 20) ? 10 : (ns == 10) ? 5 : (ns == 5) ? 2 : 1;
    const int nPerS = N_MEM / ns;

    k_prep     <<<784, 256, 0, stream>>>(key, keyb);
    k_dots_mfma<<<(NWAVES + 3) / 4, 256, 0, stream>>>(keyb, mem, dots_part, mn2_part);
    k_reduce   <<<250, 256, 0, stream>>>(dots_part, mn2_part, dots, mn2);
    k_softmax  <<<B_KEYS, 512, 0, stream>>>(key, dots, mn2, w);
    k_read     <<<49 * ns, 128, 0, stream>>>(mem, w, part, nPerS);
    k_finish   <<<784, 256, 0, stream>>>(part, out, ns);
}

// Round 7
// 377.315 us; speedup vs baseline: 1.0392x; 1.0392x over previous
//
#include <hip/hip_runtime.h>
#include <math.h>

// Problem constants
#define D_ELEMS 25088   // C*H*W = 512*7*7
#define D4      6272    // D_ELEMS / 4
#define N_MEM   2000
#define B_KEYS  32
#define PI_2F   1.570795f   // 3.14159 / 2, matches reference
#define EPSF    1e-8f
#define NSLICE  49          // k-slices for k_dots_mfma
#define KSLICE  512         // 25088 / 49
#define KSTEPS  16          // KSLICE / 32
#define NWAVES  (125 * NSLICE)   // 6125 (nt,s) wave-tasks
#define RTILE   100         // n-rows per LDS w-tile in k_read

using short8 = __attribute__((ext_vector_type(8))) short;   // 8 bf16 A/B frag
using short4v = __attribute__((ext_vector_type(4))) short;
using f32x4  = __attribute__((ext_vector_type(4))) float;   // C/D frag

// ws layout (floats):
//   keyb (bf16 keys, as shorts)   : [0, 401408)
//   dots_part [49][2000][32]      : [401408, 3537408)
//   mn2_part  [49][2000]          : [3537408, 3635408)
//   dots      [2000][32]          : [3635408, 3699408)
//   mn2       [2000]              : [3699408, 3701408)
//   knorm     [32]                : [3701408, 3701440)
//   w         [2000][32]          : [3701440, 3765440)   (16B aligned)
//   partial [ns][32][25088]       : [3765440, +ns*802816) (16B aligned)

__device__ inline short f2bf(float x) {   // fp32 -> bf16 RNE (inputs finite)
    union { float f; unsigned u; } v; v.f = x;
    unsigned r = v.u + 0x7fffu + ((v.u >> 16) & 1u);
    return (short)(r >> 16);
}

// Convert keys fp32 -> bf16. 802816 elems, 4 per thread, grid 784*256.
__global__ __launch_bounds__(256) void k_prep(const float* __restrict__ key,
                                              short* __restrict__ keyb) {
    const int i = blockIdx.x * 256 + threadIdx.x;   // float4 index
    const float4 f = ((const float4*)key)[i];
    short4v s; s[0] = f2bf(f.x); s[1] = f2bf(f.y); s[2] = f2bf(f.z); s[3] = f2bf(f.w);
    ((short4v*)keyb)[i] = s;
}

// knorm[b] = max(||key[b]||, eps). 32 blocks x 256 threads, shuffle reduce.
__global__ __launch_bounds__(256) void k_knorm(const float* __restrict__ key,
                                               float* __restrict__ knorm) {
    const int b   = blockIdx.x;
    const int tid = threadIdx.x;
    const float4* K4 = (const float4*)(key + (size_t)b * D_ELEMS);
    float ks = 0.f;
    for (int i = tid; i < D4; i += 256) {
        const float4 f = K4[i];
        ks += f.x * f.x + f.y * f.y + f.z * f.z + f.w * f.w;
    }
#pragma unroll
    for (int o = 1; o < 64; o <<= 1) ks += __shfl_xor(ks, o, 64);
    __shared__ float sred[4];
    if ((tid & 63) == 0) sred[tid >> 6] = ks;
    __syncthreads();
    if (tid == 0)
        knorm[b] = fmaxf(sqrtf(sred[0] + sred[1] + sred[2] + sred[3]), EPSF);
}

// dots_part[s][n][b] = sum_{k in slice s} key[b][k]*mem[n][k]  (bf16 MFMA)
// mn2_part[s][n]     = sum_{k in slice s} mem[n][k]^2          (fp32)
// 6125 wave-tasks PACKED 4 waves per 256-thread block: single-wave
// workgroups hit the per-CU workgroup cap (~16), stranding half the wave
// slots; packing restores ~24 resident waves/CU -> BW-saturated (in-flight
// 6 KB/wave x 24 >> 9.2 KB/CU needed at ~900cy HBM latency).
__global__ __launch_bounds__(256) void k_dots_mfma(const short* __restrict__ keyb,
                                                  const float* __restrict__ mem,
                                                  float* __restrict__ dots_part,
                                                  float* __restrict__ mn2_part) {
    const int wid = blockIdx.x * 4 + (threadIdx.x >> 6);  // wave task id
    if (wid >= NWAVES) return;                             // 3-slot pad
    const int nt   = wid / NSLICE;            // 0..124
    const int s    = wid % NSLICE;            // 0..48
    const int n0   = nt * 16;
    const int lane = threadIdx.x & 63;
    const int quad = lane >> 4;
    const int l16  = lane & 15;
    const int k0   = s * KSLICE + quad * 8;   // this lane's k base (floats)

    const short* a0p = keyb + (size_t)l16 * D_ELEMS + k0;          // keys 0..15
    const short* a1p = keyb + (size_t)(16 + l16) * D_ELEMS + k0;   // keys 16..31
    const float4* bp = (const float4*)(mem + (size_t)(n0 + l16) * D_ELEMS + k0);

    f32x4 acc0 = {0.f, 0.f, 0.f, 0.f};
    f32x4 acc1 = {0.f, 0.f, 0.f, 0.f};
    float msq = 0.f;

    // depth-1 prefetch: loads for step t+1 issue before the cvt+mfma of t
    short8 a0 = *(const short8*)a0p;
    short8 a1 = *(const short8*)a1p;
    float4 f0 = bp[0], f1 = bp[1];

    for (int t = 0; t < KSTEPS; ++t) {
        const short8 a0c = a0, a1c = a1;
        const float4 f0c = f0, f1c = f1;
        if (t + 1 < KSTEPS) {                 // wave-uniform branch
            a0 = *(const short8*)(a0p + (t + 1) * 32);
            a1 = *(const short8*)(a1p + (t + 1) * 32);
            f0 = bp[(t + 1) * 8];
            f1 = bp[(t + 1) * 8 + 1];
        }
        msq += f0c.x * f0c.x + f0c.y * f0c.y + f0c.z * f0c.z + f0c.w * f0c.w
             + f1c.x * f1c.x + f1c.y * f1c.y + f1c.z * f1c.z + f1c.w * f1c.w;
        short8 b;
        b[0] = f2bf(f0c.x); b[1] = f2bf(f0c.y); b[2] = f2bf(f0c.z); b[3] = f2bf(f0c.w);
        b[4] = f2bf(f1c.x); b[5] = f2bf(f1c.y); b[6] = f2bf(f1c.z); b[7] = f2bf(f1c.w);
        acc0 = __builtin_amdgcn_mfma_f32_16x16x32_bf16(a0c, b, acc0, 0, 0, 0);
        acc1 = __builtin_amdgcn_mfma_f32_16x16x32_bf16(a1c, b, acc1, 0, 0, 0);
    }

    // D[row=quad*4+r][col=l16]; row = key index (per m-half), col = n index
    float* dp = dots_part + (size_t)(s * N_MEM + n0 + l16) * B_KEYS;
#pragma unroll
    for (int r = 0; r < 4; ++r) {
        dp[quad * 4 + r]      = acc0[r];
        dp[16 + quad * 4 + r] = acc1[r];
    }

    // reduce msq across the 4 quads of each n-row (lanes l16, l16+16, ...)
    msq += __shfl_xor(msq, 16, 64);
    msq += __shfl_xor(msq, 32, 64);
    if (lane < 16) mn2_part[s * N_MEM + n0 + lane] = msq;
}

// Collapse the 49 slice partials: dots[n][b], mn2[n]. Coalesced. grid 250.
__global__ __launch_bounds__(256) void k_reduce(const float* __restrict__ dots_part,
                                                const float* __restrict__ mn2_part,
                                                float* __restrict__ dots,
                                                float* __restrict__ mn2) {
    const int gid = blockIdx.x * 256 + threadIdx.x;   // 0..63999
    float ds = 0.f;
#pragma unroll
    for (int s = 0; s < NSLICE; ++s) ds += dots_part[s * (N_MEM * B_KEYS) + gid];
    dots[gid] = ds;
    if (gid < N_MEM) {
        float ms = 0.f;
#pragma unroll
        for (int s = 0; s < NSLICE; ++s) ms += mn2_part[s * N_MEM + gid];
        mn2[gid] = ms;
    }
}

// per-b: cos -> tan -> softmax over n -> w. knorm precomputed by k_knorm.
__global__ __launch_bounds__(512) void k_softmax(const float* __restrict__ knormArr,
                                                 const float* __restrict__ dots,
                                                 const float* __restrict__ mn2,
                                                 float* __restrict__ w) {
    const int b   = blockIdx.x;
    const int tid = threadIdx.x;
    __shared__ float sred[512];
    __shared__ float xbuf[N_MEM];
    const float knorm = knormArr[b];

    float mx = -1e30f;
    for (int n = tid; n < N_MEM; n += 512) {
        const float mn = fmaxf(sqrtf(mn2[n]), EPSF);
        const float x  = __tanf((dots[n * B_KEYS + b] / (knorm * mn)) * PI_2F);
        xbuf[n] = x;
        mx = fmaxf(mx, x);
    }
    sred[tid] = mx;
    __syncthreads();
    for (int o = 256; o; o >>= 1) {
        if (tid < o) sred[tid] = fmaxf(sred[tid], sred[tid + o]);
        __syncthreads();
    }
    mx = sred[0];
    __syncthreads();

    float sm = 0.f;
    for (int n = tid; n < N_MEM; n += 512) {   // cache exp in xbuf (own slots)
        const float e = __expf(xbuf[n] - mx);
        xbuf[n] = e;
        sm += e;
    }
    sred[tid] = sm;
    __syncthreads();
    for (int o = 256; o; o >>= 1) {
        if (tid < o) sred[tid] += sred[tid + o];
        __syncthreads();
    }
    const float inv = 1.f / sred[0];

    for (int n = tid; n < N_MEM; n += 512)
        w[n * B_KEYS + b] = xbuf[n] * inv;
}

// partial[s][b][d] = sum_{n in split s} w[n][b] * mem[n][d]
// 256-thread blocks (4 waves = TLP kept: 980 blocks -> 15.3 waves/CU at
// ns=20), waves split b (2 halves) x d (2 halves): each thread owns one
// float4 column for 16 b (acc[16][4] = 64 VGPRs). mem redundancy is 2x
// (was 4x in R1/R5; the twin wave hits L1). w broadcast from a 100-row
// LDS tile -- uniform wave address = conflict-free broadcast. Plain
// affine loop + unroll-4; NO manual prefetch ring (R4 lesson: rings with
// clamp ternaries collapse the register allocator).
__global__ __launch_bounds__(256, 2) void k_read(const float* __restrict__ mem,
                                                 const float* __restrict__ w,
                                                 float* __restrict__ partial,
                                                 int nPerS) {
    const int db   = blockIdx.x % 49;
    const int s    = blockIdx.x / 49;
    const int n0   = s * nPerS;
    const int lane = threadIdx.x & 63;
    const int wv   = threadIdx.x >> 6;          // 0..3
    const int bh   = wv & 1;                    // b-half: 0 -> b0..15, 1 -> b16..31
    const int dh   = wv >> 1;                   // d-half within the 128-col block
    const int d4   = db * 128 + dh * 64 + lane; // float4 column, < 6272 exactly

    const float4* M4 = (const float4*)mem;
    const float4* W4 = (const float4*)w;        // [n][8] float4
    __shared__ float4 wls[RTILE * 8];           // 100 n x 32 b = 12.8 KB

    float acc[16][4];
#pragma unroll
    for (int i = 0; i < 16; ++i) {
        acc[i][0] = 0.f; acc[i][1] = 0.f; acc[i][2] = 0.f; acc[i][3] = 0.f;
    }

    for (int c0 = 0; c0 < nPerS; c0 += RTILE) { // nPerS is a multiple of 100
        __syncthreads();
        for (int i = threadIdx.x; i < RTILE * 8; i += 256)
            wls[i] = W4[(size_t)(n0 + c0) * 8 + i];
        __syncthreads();

        const float4* mp = M4 + (size_t)(n0 + c0) * D4 + d4;
#pragma unroll 4
        for (int nn = 0; nn < RTILE; ++nn) {
            const float4 mc = mp[(size_t)nn * D4];
#pragma unroll
            for (int q = 0; q < 4; ++q) {
                const float4 wq = wls[nn * 8 + bh * 4 + q];  // broadcast read
                const int b0 = q * 4;
                acc[b0+0][0] += wq.x * mc.x; acc[b0+0][1] += wq.x * mc.y;
                acc[b0+0][2] += wq.x * mc.z; acc[b0+0][3] += wq.x * mc.w;
                acc[b0+1][0] += wq.y * mc.x; acc[b0+1][1] += wq.y * mc.y;
                acc[b0+1][2] += wq.y * mc.z; acc[b0+1][3] += wq.y * mc.w;
                acc[b0+2][0] += wq.z * mc.x; acc[b0+2][1] += wq.z * mc.y;
                acc[b0+2][2] += wq.z * mc.z; acc[b0+2][3] += wq.z * mc.w;
                acc[b0+3][0] += wq.w * mc.x; acc[b0+3][1] += wq.w * mc.y;
                acc[b0+3][2] += wq.w * mc.z; acc[b0+3][3] += wq.w * mc.w;
            }
        }
    }

    float4* P4 = (float4*)partial;
#pragma unroll
    for (int b = 0; b < 16; ++b)
        P4[(size_t)(s * B_KEYS + bh * 16 + b) * D4 + d4] =
            make_float4(acc[b][0], acc[b][1], acc[b][2], acc[b][3]);
}

__global__ __launch_bounds__(256) void k_finish(const float* __restrict__ partial,
                                                float* __restrict__ out, int ns) {
    const int i = blockIdx.x * 256 + threadIdx.x;   // float4 index, grid 784*256
    const float4* P4 = (const float4*)partial;
    float4 sum = P4[i];
    for (int s = 1; s < ns; ++s) {
        const float4 p = P4[(size_t)s * (B_KEYS * D4) + i];
        sum.x += p.x; sum.y += p.y; sum.z += p.z; sum.w += p.w;
    }
    ((float4*)out)[i] = sum;
}

extern "C" void kernel_launch(void* const* d_in, const int* in_sizes, int n_in,
                              void* d_out, int out_size, void* d_ws, size_t ws_size,
                              hipStream_t stream) {
    (void)in_sizes; (void)n_in; (void)out_size;
    const float* key = (const float*)d_in[0];
    const float* mem = (const float*)d_in[1];
    float* out = (float*)d_out;
    float* ws  = (float*)d_ws;

    short* keyb      = (short*)ws;      // 802816 shorts = 401408 floats
    float* dots_part = ws + 401408;     // 3136000 floats
    float* mn2_part  = ws + 3537408;    // 98000 floats
    float* dots      = ws + 3635408;    // 64000 floats
    float* mn2       = ws + 3699408;    // 2000 floats
    float* knorm     = ws + 3701408;    // 32 floats
    float* w         = ws + 3701440;    // 64000 floats (16B aligned)
    float* part      = ws + 3765440;    // ns * 802816 floats (16B aligned)

    // ns ladder keeps nPerS a multiple of RTILE=100: 20, 10, 5, 2, 1
    int ns = 20;
    while (ns > 1 && (size_t)(3765440 + (size_t)ns * 802816) * 4 > ws_size)
        ns = (ns == 20) ? 10 : (ns == 10) ? 5 : (ns == 5) ? 2 : 1;
    const int nPerS = N_MEM / ns;

    k_prep     <<<784, 256, 0, stream>>>(key, keyb);
    k_knorm    <<<B_KEYS, 256, 0, stream>>>(key, knorm);
    k_dots_mfma<<<(NWAVES + 3) / 4, 256, 0, stream>>>(keyb, mem, dots_part, mn2_part);
    k_reduce   <<<250, 256, 0, stream>>>(dots_part, mn2_part, dots, mn2);
    k_softmax  <<<B_KEYS, 512, 0, stream>>>(knorm, dots, mn2, w);
    k_read     <<<49 * ns, 256, 0, stream>>>(mem, w, part, nPerS);
    k_finish   <<<784, 256, 0, stream>>>(part, out, ns);
}